// Round 11
// baseline (428.292 us; speedup 1.0000x reference)
//
#include <hip/hip_runtime.h>

#define NN 50000
#define NPAD 50048           // padded to multiple of 64 rows
#define EE 800000
#define RR 8
#define NR (NN * RR)         // 400000 (dst,rel) counters (for norm only)
#define KC 1152              // output cols: 128 root + 8*128 relations

typedef __attribute__((ext_vector_type(8))) short bf16x8;
typedef __attribute__((ext_vector_type(4))) float f32x4;

__device__ __forceinline__ unsigned short f2bf(float f) {
    unsigned u = __builtin_bit_cast(unsigned, f);
    u = (u + 0x7FFF + ((u >> 16) & 1)) >> 16;   // RNE
    return (unsigned short)u;
}
__device__ __forceinline__ float bf2f(unsigned short s) {
    return __builtin_bit_cast(float, (unsigned)s << 16);
}

// ---------------- graph preprocessing ----------------
__global__ void zero_i32(int* __restrict__ p, int n) {
    int i = blockIdx.x * blockDim.x + threadIdx.x;
    if (i < n) p[i] = 0;
}

__global__ void count_deg(const int* __restrict__ dst, const int* __restrict__ et,
                          int* __restrict__ degRel) {
    int e = blockIdx.x * blockDim.x + threadIdx.x;
    if (e < EE) atomicAdd(&degRel[dst[e] * RR + et[e]], 1);
}

__global__ void sum8(const int* __restrict__ degRel, int* __restrict__ degD) {
    int n = blockIdx.x * blockDim.x + threadIdx.x;
    if (n >= NN) return;
    int s = 0;
    #pragma unroll
    for (int r = 0; r < RR; ++r) s += degRel[n * RR + r];
    degD[n] = s;
}

// exclusive scan over n ints: 1024 per block
__global__ __launch_bounds__(256) void scan1(const int* __restrict__ in, int* __restrict__ out,
                                             int* __restrict__ bsum, int n) {
    __shared__ int sh[256];
    int t = threadIdx.x;
    int base = blockIdx.x * 1024 + t * 4;
    int v[4]; int s = 0;
    #pragma unroll
    for (int i = 0; i < 4; ++i) { int idx = base + i; v[i] = (idx < n) ? in[idx] : 0; s += v[i]; }
    sh[t] = s; __syncthreads();
    for (int off = 1; off < 256; off <<= 1) {
        int x = (t >= off) ? sh[t - off] : 0; __syncthreads();
        if (t >= off) sh[t] += x; __syncthreads();
    }
    if (t == 255) bsum[blockIdx.x] = sh[255];
    int run = sh[t] - s;
    #pragma unroll
    for (int i = 0; i < 4; ++i) { int idx = base + i; if (idx < n) out[idx] = run; run += v[i]; }
}

__global__ __launch_bounds__(256) void scan2(int* __restrict__ bsum, int nb) {
    __shared__ int sh[256];
    int t = threadIdx.x; int carry = 0;
    for (int base = 0; base < nb; base += 256) {
        int idx = base + t;
        int v = (idx < nb) ? bsum[idx] : 0;
        sh[t] = v; __syncthreads();
        for (int off = 1; off < 256; off <<= 1) {
            int x = (t >= off) ? sh[t - off] : 0; __syncthreads();
            if (t >= off) sh[t] += x; __syncthreads();
        }
        int incl = sh[t];
        int total = sh[255];
        if (idx < nb) bsum[idx] = carry + incl - v;   // exclusive
        carry += total;
        __syncthreads();
    }
}

__global__ __launch_bounds__(256) void scan3(int* __restrict__ out, const int* __restrict__ bsum, int n) {
    int base = blockIdx.x * 1024 + threadIdx.x * 4;
    int add = bsum[blockIdx.x];
    #pragma unroll
    for (int i = 0; i < 4; ++i) { int idx = base + i; if (idx < n) out[idx] += add; }
}

__global__ void set_last(int* __restrict__ segD) {
    segD[NN] = EE;
}

// rec[pos] = (element offset into y) << 6 | deg(dst,rel)
__global__ void scatter2(const int* __restrict__ src, const int* __restrict__ dst,
                         const int* __restrict__ et, const int* __restrict__ segD,
                         const int* __restrict__ degRel, int* __restrict__ cursorD,
                         unsigned* __restrict__ rec) {
    int e = blockIdx.x * blockDim.x + threadIdx.x;
    if (e >= EE) return;
    int d_ = dst[e], r_ = et[e], s_ = src[e];
    int pos = segD[d_] + atomicAdd(&cursorD[d_], 1);
    int dg = degRel[d_ * RR + r_]; if (dg > 63) dg = 63;
    rec[pos] = ((unsigned)(s_ * KC + 128 + r_ * 128) << 6) | (unsigned)dg;
}

// ---------------- x -> bf16 (pad rows zeroed) ----------------
__global__ __launch_bounds__(256) void xcvt(const float* __restrict__ x,
                                            unsigned short* __restrict__ xbf) {
    size_t i = ((size_t)blockIdx.x * 256 + threadIdx.x) * 4;
    if (i >= (size_t)NPAD * 128) return;
    unsigned short o[4];
    if (i < (size_t)NN * 128) {
        float4 v = *reinterpret_cast<const float4*>(x + i);
        o[0] = f2bf(v.x); o[1] = f2bf(v.y); o[2] = f2bf(v.z); o[3] = f2bf(v.w);
    } else {
        o[0] = o[1] = o[2] = o[3] = 0;
    }
    unsigned lo = (unsigned)o[0] | ((unsigned)o[1] << 16);
    unsigned hi = (unsigned)o[2] | ((unsigned)o[3] << 16);
    *reinterpret_cast<uint2*>(xbf + i) = make_uint2(lo, hi);
}

// ---------------- weight panel, FRAGMENT-MAJOR: Bf[p][cg][s][lane][e] ----------------
// Fragment for (p,cg,s): lane (l15,lhi) holds B[k=(s*4+lhi)*8+e][col=p*128+cg*16+l15]
// where B rows: k<... col<128 -> root[k][col]; else W[r][k][col'].
__global__ void build_bt3(const float* __restrict__ W, const float* __restrict__ root,
                          unsigned short* __restrict__ Bf) {
    int i = blockIdx.x * blockDim.x + threadIdx.x;
    if (i >= 9 * 8 * 4 * 64 * 8) return;         // 147456 = 1152*128
    int e = i & 7, lane = (i >> 3) & 63, s = (i >> 9) & 3, cg = (i >> 11) & 7, p = i >> 14;
    int col = p * 128 + cg * 16 + (lane & 15);
    int k = (s * 4 + (lane >> 4)) * 8 + e;
    float v;
    if (col < 128) v = root[k * 128 + col];
    else {
        int r = (col - 128) >> 7, cp = (col - 128) & 127;
        v = W[((size_t)r * 128 + k) * 128 + cp];
    }
    Bf[i] = f2bf(v);
}

// ---------------- GEMM: y = hin @ [root | W_0..W_7]  ([NPAD,128] @ [128,1152]) ----------------
// Barrier-free, LDS-free. B fragments streamed from L2 (288 KB, fragment-major,
// 16B/lane fully-coalesced loads). A-frags in regs (hin read once). Swapped-operand
// MFMA -> lane l15 = y-row, lhi*4+reg = y-col quad -> packed 8B stores.
__global__ __launch_bounds__(256) void gemm_y(
    const unsigned short* __restrict__ hin,   // [NPAD][128]
    const unsigned short* __restrict__ Bf,    // [9][8][4][64][8]
    unsigned short* __restrict__ y)           // [NPAD][1152]
{
    const int tid = threadIdx.x;
    const int w = tid >> 6, lane = tid & 63;
    const int l15 = lane & 15, lhi = lane >> 4;
    const int row0 = blockIdx.x * 64;
    const int gn = row0 + w * 16 + l15;

    // A fragments: this lane's h-row, 4 k-steps of 8
    const unsigned short* abase = hin + ((size_t)gn << 7) + lhi * 8;
    bf16x8 rf[4];
    rf[0] = *reinterpret_cast<const bf16x8*>(abase);
    rf[1] = *reinterpret_cast<const bf16x8*>(abase + 32);
    rf[2] = *reinterpret_cast<const bf16x8*>(abase + 64);
    rf[3] = *reinterpret_cast<const bf16x8*>(abase + 96);

    const unsigned short* bbase = Bf + lane * 8;
    unsigned short* yrow = y + (size_t)gn * KC;
    const bool wr = (gn < NN);

    for (int p = 0; p < 9; ++p) {
        f32x4 acc[8];
        #pragma unroll
        for (int i = 0; i < 8; ++i) acc[i] = (f32x4)(0.f);
        #pragma unroll
        for (int s = 0; s < 4; ++s) {
            #pragma unroll
            for (int cg = 0; cg < 8; ++cg) {
                bf16x8 bv = *reinterpret_cast<const bf16x8*>(
                    bbase + (size_t)(((p * 8 + cg) * 4 + s) * 64) * 8);
                acc[cg] = __builtin_amdgcn_mfma_f32_16x16x32_bf16(bv, rf[s], acc[cg], 0, 0, 0);
            }
        }
        if (wr) {
            #pragma unroll
            for (int cg = 0; cg < 8; ++cg) {
                uint2 pk;
                pk.x = (unsigned)f2bf(acc[cg][0]) | ((unsigned)f2bf(acc[cg][1]) << 16);
                pk.y = (unsigned)f2bf(acc[cg][2]) | ((unsigned)f2bf(acc[cg][3]) << 16);
                *reinterpret_cast<uint2*>(yrow + p * 128 + cg * 16 + lhi * 4) = pk;
            }
        }
    }
}

// ---------------- aggregation: hout[n] = relu(y[n][0:128] + bias + sum_e norm_e * y[off_e..]) ----------------
// One wave per node. Lane = (eg, fl): eg = edge slot (4 concurrent), fl = 16B feature slice.
// FINAL: fuse the fc dot-product, write float out[n] instead of hout.
template<bool FINAL>
__global__ __launch_bounds__(256) void agg3(
    const unsigned short* __restrict__ y,     // [NPAD][1152]
    const unsigned* __restrict__ rec,         // [EE] off<<6|deg, sorted by dst
    const int* __restrict__ segD,             // [NN+1]
    const float* __restrict__ bias,           // [128]
    unsigned short* __restrict__ hout,        // [NPAD][128]  (if !FINAL)
    const float* __restrict__ fcw,            // [128]        (if FINAL)
    const float* __restrict__ fcb,            // [1]          (if FINAL)
    float* __restrict__ fout)                 // [NN]         (if FINAL)
{
    const int w = threadIdx.x >> 6, lane = threadIdx.x & 63;
    const int n = blockIdx.x * 4 + w;
    if (n >= NPAD) return;
    const int fl = lane & 15, eg = lane >> 4;

    float fa[8];
    #pragma unroll
    for (int i = 0; i < 8; ++i) fa[i] = 0.f;

    if (n < NN) {
        const int s0 = segD[n], s1 = segD[n + 1];
        for (int base = s0; base < s1; base += 64) {
            const int ld = min(64, s1 - base);
            int idx = base + lane; if (idx > s1 - 1) idx = s1 - 1;
            const int rcL = (int)rec[idx];
            for (int t0 = 0; t0 < ld; t0 += 16) {
                uint4 L[4]; float nm[4];
                #pragma unroll
                for (int t = 0; t < 4; ++t) {
                    int j = t0 + t * 4 + eg;
                    int rcj = __shfl(rcL, j & 63);
                    bool on = (j < ld);
                    nm[t] = on ? __builtin_amdgcn_rcpf((float)(rcj & 63)) : 0.f;
                    unsigned off = ((unsigned)rcj) >> 6;
                    const unsigned short* p = y + (size_t)(on ? off : 0u) + fl * 8;
                    L[t] = *reinterpret_cast<const uint4*>(p);
                }
                #pragma unroll
                for (int t = 0; t < 4; ++t) {
                    fa[0] += nm[t] * bf2f((unsigned short)(L[t].x & 0xFFFF));
                    fa[1] += nm[t] * bf2f((unsigned short)(L[t].x >> 16));
                    fa[2] += nm[t] * bf2f((unsigned short)(L[t].y & 0xFFFF));
                    fa[3] += nm[t] * bf2f((unsigned short)(L[t].y >> 16));
                    fa[4] += nm[t] * bf2f((unsigned short)(L[t].z & 0xFFFF));
                    fa[5] += nm[t] * bf2f((unsigned short)(L[t].z >> 16));
                    fa[6] += nm[t] * bf2f((unsigned short)(L[t].w & 0xFFFF));
                    fa[7] += nm[t] * bf2f((unsigned short)(L[t].w >> 16));
                }
            }
        }
        // reduce across the 4 edge groups
        #pragma unroll
        for (int i = 0; i < 8; ++i) {
            fa[i] += __shfl_xor(fa[i], 16);
            fa[i] += __shfl_xor(fa[i], 32);
        }
    }

    if (eg == 0) {
        if (n < NN) {
            const unsigned short* rp = y + (size_t)n * KC + fl * 8;
            uint4 rv = *reinterpret_cast<const uint4*>(rp);
            float4 b0 = *reinterpret_cast<const float4*>(bias + fl * 8);
            float4 b1 = *reinterpret_cast<const float4*>(bias + fl * 8 + 4);
            float r[8];
            r[0] = bf2f((unsigned short)(rv.x & 0xFFFF)); r[1] = bf2f((unsigned short)(rv.x >> 16));
            r[2] = bf2f((unsigned short)(rv.y & 0xFFFF)); r[3] = bf2f((unsigned short)(rv.y >> 16));
            r[4] = bf2f((unsigned short)(rv.z & 0xFFFF)); r[5] = bf2f((unsigned short)(rv.z >> 16));
            r[6] = bf2f((unsigned short)(rv.w & 0xFFFF)); r[7] = bf2f((unsigned short)(rv.w >> 16));
            float bb[8] = {b0.x, b0.y, b0.z, b0.w, b1.x, b1.y, b1.z, b1.w};
            float v[8];
            #pragma unroll
            for (int i = 0; i < 8; ++i) v[i] = fmaxf(fa[i] + r[i] + bb[i], 0.f);
            if constexpr (!FINAL) {
                uint4 pk;
                unsigned short o[8];
                #pragma unroll
                for (int i = 0; i < 8; ++i) o[i] = f2bf(v[i]);
                pk.x = (unsigned)o[0] | ((unsigned)o[1] << 16);
                pk.y = (unsigned)o[2] | ((unsigned)o[3] << 16);
                pk.z = (unsigned)o[4] | ((unsigned)o[5] << 16);
                pk.w = (unsigned)o[6] | ((unsigned)o[7] << 16);
                *reinterpret_cast<uint4*>(hout + (size_t)n * 128 + fl * 8) = pk;
            } else {
                // note: match reference h3 (bf16 rounded) before fc
                float dp = 0.f;
                #pragma unroll
                for (int i = 0; i < 8; ++i) dp += bf2f(f2bf(v[i])) * fcw[fl * 8 + i];
                dp += __shfl_xor(dp, 1);
                dp += __shfl_xor(dp, 2);
                dp += __shfl_xor(dp, 4);
                dp += __shfl_xor(dp, 8);
                if (fl == 0) fout[n] = dp + fcb[0];
            }
        } else if constexpr (!FINAL) {
            *reinterpret_cast<uint4*>(hout + (size_t)n * 128 + fl * 8) = make_uint4(0, 0, 0, 0);
        }
    }
}

extern "C" void kernel_launch(void* const* d_in, const int* in_sizes, int n_in,
                              void* d_out, int out_size, void* d_ws, size_t ws_size,
                              hipStream_t stream) {
    const float* x     = (const float*)d_in[0];
    const int*   ei    = (const int*)d_in[1];
    const int*   etype = (const int*)d_in[2];
    const float* W[3]    = {(const float*)d_in[3], (const float*)d_in[6], (const float*)d_in[9]};
    const float* root[3] = {(const float*)d_in[4], (const float*)d_in[7], (const float*)d_in[10]};
    const float* bias[3] = {(const float*)d_in[5], (const float*)d_in[8], (const float*)d_in[11]};
    const float* fcw = (const float*)d_in[12];
    const float* fcb = (const float*)d_in[13];
    const int* src = ei;
    const int* dst = ei + EE;

    char* ws = (char*)d_ws;
    auto alloc = [&](size_t bytes) { char* p = ws; ws += (bytes + 255) & ~(size_t)255; return p; };
    int* degRel   = (int*)alloc(NR * sizeof(int));
    int* cursorD  = (int*)alloc(NN * sizeof(int));       // contiguous after degRel
    int* degD     = (int*)alloc(NN * sizeof(int));
    int* segD     = (int*)alloc((NN + 2) * sizeof(int));
    int* bsum     = (int*)alloc(512 * sizeof(int));
    unsigned* rec = (unsigned*)alloc((size_t)EE * sizeof(unsigned));
    unsigned short* Bfg  = (unsigned short*)alloc((size_t)3 * KC * 128 * sizeof(short));
    unsigned short* xbf  = (unsigned short*)alloc((size_t)NPAD * 128 * sizeof(short));
    unsigned short* h1   = (unsigned short*)alloc((size_t)NPAD * 128 * sizeof(short));
    unsigned short* h2   = (unsigned short*)alloc((size_t)NPAD * 128 * sizeof(short));
    unsigned short* yall = (unsigned short*)alloc((size_t)NPAD * KC * sizeof(short));

    // --- graph preprocessing ---
    zero_i32<<<(NR + NN + 255) / 256, 256, 0, stream>>>(degRel, NR + NN);   // degRel + cursorD
    count_deg<<<(EE + 255) / 256, 256, 0, stream>>>(dst, etype, degRel);
    sum8<<<(NN + 255) / 256, 256, 0, stream>>>(degRel, degD);
    const int nScanBlk = (NN + 1023) / 1024;   // 49
    scan1<<<nScanBlk, 256, 0, stream>>>(degD, segD, bsum, NN);
    scan2<<<1, 256, 0, stream>>>(bsum, nScanBlk);
    scan3<<<nScanBlk, 256, 0, stream>>>(segD, bsum, NN);
    set_last<<<1, 1, 0, stream>>>(segD);
    scatter2<<<(EE + 255) / 256, 256, 0, stream>>>(src, dst, etype, segD, degRel, cursorD, rec);

    // --- input conversion + weight panels ---
    xcvt<<<((NPAD * 128 / 4) + 255) / 256, 256, 0, stream>>>(x, xbf);
    const int btN = KC * 128;
    for (int l = 0; l < 3; ++l)
        build_bt3<<<(btN + 255) / 256, 256, 0, stream>>>(W[l], root[l], Bfg + (size_t)l * btN);

    // --- layers ---
    const int ggrid = NPAD / 64;         // 782
    const int aggGrid = NPAD / 4;        // 12512
    const unsigned short* hin = xbf;
    unsigned short* houts[2] = {h1, h2};
    for (int l = 0; l < 3; ++l) {
        gemm_y<<<ggrid, 256, 0, stream>>>(hin, Bfg + (size_t)l * btN, yall);
        if (l < 2) {
            agg3<false><<<aggGrid, 256, 0, stream>>>(yall, rec, segD, bias[l], houts[l],
                                                     nullptr, nullptr, nullptr);
            hin = houts[l];
        } else {
            agg3<true><<<aggGrid, 256, 0, stream>>>(yall, rec, segD, bias[l], nullptr,
                                                    fcw, fcb, (float*)d_out);
        }
    }
}

// Round 12
// 328.250 us; speedup vs baseline: 1.3048x; 1.3048x over previous
//
#include <hip/hip_runtime.h>

#define NN 50000
#define NPAD 50048           // padded to multiple of 64 rows
#define EE 800000
#define RR 8
#define NR (NN * RR)         // 400000 (dst,rel) counters (for norm only)
#define KC 1152              // output cols: 128 root + 8*128 relations

typedef __attribute__((ext_vector_type(8))) short bf16x8;
typedef __attribute__((ext_vector_type(4))) float f32x4;

__device__ __forceinline__ unsigned short f2bf(float f) {
    unsigned u = __builtin_bit_cast(unsigned, f);
    u = (u + 0x7FFF + ((u >> 16) & 1)) >> 16;   // RNE
    return (unsigned short)u;
}
__device__ __forceinline__ float bf2f(unsigned short s) {
    return __builtin_bit_cast(float, (unsigned)s << 16);
}

#define GLDS16(g, l) __builtin_amdgcn_global_load_lds( \
    (const __attribute__((address_space(1))) void*)(g), \
    (__attribute__((address_space(3))) void*)(l), 16, 0, 0)

// ---------------- graph preprocessing ----------------
__global__ void zero_i32(int* __restrict__ p, int n) {
    int i = blockIdx.x * blockDim.x + threadIdx.x;
    if (i < n) p[i] = 0;
}

__global__ void count_deg(const int* __restrict__ dst, const int* __restrict__ et,
                          int* __restrict__ degRel) {
    int e = blockIdx.x * blockDim.x + threadIdx.x;
    if (e < EE) atomicAdd(&degRel[dst[e] * RR + et[e]], 1);
}

__global__ void sum8(const int* __restrict__ degRel, int* __restrict__ degD) {
    int n = blockIdx.x * blockDim.x + threadIdx.x;
    if (n >= NN) return;
    int s = 0;
    #pragma unroll
    for (int r = 0; r < RR; ++r) s += degRel[n * RR + r];
    degD[n] = s;
}

// exclusive scan over n ints: 1024 per block
__global__ __launch_bounds__(256) void scan1(const int* __restrict__ in, int* __restrict__ out,
                                             int* __restrict__ bsum, int n) {
    __shared__ int sh[256];
    int t = threadIdx.x;
    int base = blockIdx.x * 1024 + t * 4;
    int v[4]; int s = 0;
    #pragma unroll
    for (int i = 0; i < 4; ++i) { int idx = base + i; v[i] = (idx < n) ? in[idx] : 0; s += v[i]; }
    sh[t] = s; __syncthreads();
    for (int off = 1; off < 256; off <<= 1) {
        int x = (t >= off) ? sh[t - off] : 0; __syncthreads();
        if (t >= off) sh[t] += x; __syncthreads();
    }
    if (t == 255) bsum[blockIdx.x] = sh[255];
    int run = sh[t] - s;
    #pragma unroll
    for (int i = 0; i < 4; ++i) { int idx = base + i; if (idx < n) out[idx] = run; run += v[i]; }
}

__global__ __launch_bounds__(256) void scan2(int* __restrict__ bsum, int nb) {
    __shared__ int sh[256];
    int t = threadIdx.x; int carry = 0;
    for (int base = 0; base < nb; base += 256) {
        int idx = base + t;
        int v = (idx < nb) ? bsum[idx] : 0;
        sh[t] = v; __syncthreads();
        for (int off = 1; off < 256; off <<= 1) {
            int x = (t >= off) ? sh[t - off] : 0; __syncthreads();
            if (t >= off) sh[t] += x; __syncthreads();
        }
        int incl = sh[t];
        int total = sh[255];
        if (idx < nb) bsum[idx] = carry + incl - v;   // exclusive
        carry += total;
        __syncthreads();
    }
}

__global__ __launch_bounds__(256) void scan3(int* __restrict__ out, const int* __restrict__ bsum, int n) {
    int base = blockIdx.x * 1024 + threadIdx.x * 4;
    int add = bsum[blockIdx.x];
    #pragma unroll
    for (int i = 0; i < 4; ++i) { int idx = base + i; if (idx < n) out[idx] += add; }
}

__global__ void set_last(int* __restrict__ segD) {
    segD[NN] = EE;
}

// rec[pos] = (element offset into y) << 6 | deg(dst,rel)
__global__ void scatter2(const int* __restrict__ src, const int* __restrict__ dst,
                         const int* __restrict__ et, const int* __restrict__ segD,
                         const int* __restrict__ degRel, int* __restrict__ cursorD,
                         unsigned* __restrict__ rec) {
    int e = blockIdx.x * blockDim.x + threadIdx.x;
    if (e >= EE) return;
    int d_ = dst[e], r_ = et[e], s_ = src[e];
    int pos = segD[d_] + atomicAdd(&cursorD[d_], 1);
    int dg = degRel[d_ * RR + r_]; if (dg > 63) dg = 63;
    rec[pos] = ((unsigned)(s_ * KC + 128 + r_ * 128) << 6) | (unsigned)dg;
}

// ---------------- x -> bf16 (pad rows zeroed) ----------------
__global__ __launch_bounds__(256) void xcvt(const float* __restrict__ x,
                                            unsigned short* __restrict__ xbf) {
    size_t i = ((size_t)blockIdx.x * 256 + threadIdx.x) * 4;
    if (i >= (size_t)NPAD * 128) return;
    unsigned short o[4];
    if (i < (size_t)NN * 128) {
        float4 v = *reinterpret_cast<const float4*>(x + i);
        o[0] = f2bf(v.x); o[1] = f2bf(v.y); o[2] = f2bf(v.z); o[3] = f2bf(v.w);
    } else {
        o[0] = o[1] = o[2] = o[3] = 0;
    }
    unsigned lo = (unsigned)o[0] | ((unsigned)o[1] << 16);
    unsigned hi = (unsigned)o[2] | ((unsigned)o[3] << 16);
    *reinterpret_cast<uint2*>(xbf + i) = make_uint2(lo, hi);
}

// ---------------- weight panel: Bt2[col][k], col in [0,1152), k in [0,128) ----------------
__global__ void build_bt2(const float* __restrict__ W, const float* __restrict__ root,
                          unsigned short* __restrict__ Bt2) {
    int i = blockIdx.x * blockDim.x + threadIdx.x;
    if (i >= KC * 128) return;
    int col = i / 128, k = i % 128;
    float v;
    if (col < 128) v = root[k * 128 + col];
    else {
        int r = (col - 128) >> 7, cp = (col - 128) & 127;
        v = W[((size_t)r * 128 + k) * 128 + cp];
    }
    Bt2[i] = f2bf(v);
}

// ---------------- GEMM: y = hin @ [root | W_0..W_7]  ([NPAD,128] @ [128,1152]) ----------------
// Grid NPAD/64. Block: 64 rows; loops over 9 col-panels of 128 (B double-buffered in LDS).
// A-fragments live in registers for the whole block (hin read ONCE from HBM).
__global__ __launch_bounds__(256, 2) void gemm_y(
    const unsigned short* __restrict__ hin,   // [NPAD][128]
    const unsigned short* __restrict__ Bt2,   // [1152][128]
    unsigned short* __restrict__ y)           // [NPAD][1152]
{
    __shared__ alignas(16) unsigned short Bs[2][128 * 128];   // 2 x 32 KB
    const int tid = threadIdx.x;
    const int w = tid >> 6, lane = tid & 63;
    const int l15 = lane & 15, lhi = lane >> 4;
    const int row0 = blockIdx.x * 64;

    auto stage = [&](int b, int p) {
        #pragma unroll
        for (int i = 0; i < 8; ++i) {
            int q = i * 256 + tid;            // chunk id 0..2047
            int col = q >> 4, c = q & 15;
            GLDS16(Bt2 + (size_t)(p * 128 + col) * 128 + ((c ^ (col & 7)) * 8), &Bs[b][q * 8]);
        }
    };

    // A fragments (4 k-steps), direct from global
    const int gn = row0 + w * 16 + l15;
    const unsigned short* abase = hin + ((size_t)gn << 7) + lhi * 8;
    bf16x8 rf[4];
    rf[0] = *reinterpret_cast<const bf16x8*>(abase);
    rf[1] = *reinterpret_cast<const bf16x8*>(abase + 32);
    rf[2] = *reinterpret_cast<const bf16x8*>(abase + 64);
    rf[3] = *reinterpret_cast<const bf16x8*>(abase + 96);

    stage(0, 0);
    __syncthreads();
    for (int p = 0; p < 9; ++p) {
        const int b = p & 1;
        if (p < 8) stage(b ^ 1, p + 1);
        f32x4 acc[8];
        #pragma unroll
        for (int i = 0; i < 8; ++i) acc[i] = (f32x4)(0.f);
        #pragma unroll
        for (int s = 0; s < 4; ++s) {
            #pragma unroll
            for (int cg = 0; cg < 8; ++cg) {
                int col = cg * 16 + l15;
                int phys = (s * 4 + lhi) ^ (col & 7);
                bf16x8 bv = *reinterpret_cast<const bf16x8*>(&Bs[b][col * 128 + phys * 8]);
                acc[cg] = __builtin_amdgcn_mfma_f32_16x16x32_bf16(rf[s], bv, acc[cg], 0, 0, 0);
            }
        }
        #pragma unroll
        for (int cg = 0; cg < 8; ++cg) {
            int col = p * 128 + cg * 16 + l15;
            #pragma unroll
            for (int rg = 0; rg < 4; ++rg) {
                int grow = row0 + w * 16 + lhi * 4 + rg;
                y[(size_t)grow * KC + col] = f2bf(acc[cg][rg]);
            }
        }
        __syncthreads();
    }
}

// ---------------- aggregation: hout[n] = relu(y[n][0:128] + bias + sum_e norm_e * y[off_e..]) ----------------
// One wave per node. Lane = (eg, fl): eg = edge slot (4 concurrent), fl = 16B feature slice.
// FINAL: fuse the fc dot-product, write float out[n] instead of hout.
template<bool FINAL>
__global__ __launch_bounds__(256) void agg3(
    const unsigned short* __restrict__ y,     // [NPAD][1152]
    const unsigned* __restrict__ rec,         // [EE] off<<6|deg, sorted by dst
    const int* __restrict__ segD,             // [NN+1]
    const float* __restrict__ bias,           // [128]
    unsigned short* __restrict__ hout,        // [NPAD][128]  (if !FINAL)
    const float* __restrict__ fcw,            // [128]        (if FINAL)
    const float* __restrict__ fcb,            // [1]          (if FINAL)
    float* __restrict__ fout)                 // [NN]         (if FINAL)
{
    const int w = threadIdx.x >> 6, lane = threadIdx.x & 63;
    const int n = blockIdx.x * 4 + w;
    if (n >= NPAD) return;
    const int fl = lane & 15, eg = lane >> 4;

    float fa[8];
    #pragma unroll
    for (int i = 0; i < 8; ++i) fa[i] = 0.f;

    if (n < NN) {
        const int s0 = segD[n], s1 = segD[n + 1];
        for (int base = s0; base < s1; base += 64) {
            const int ld = min(64, s1 - base);
            int idx = base + lane; if (idx > s1 - 1) idx = s1 - 1;
            const int rcL = (int)rec[idx];
            for (int t0 = 0; t0 < ld; t0 += 16) {
                uint4 L[4]; float nm[4];
                #pragma unroll
                for (int t = 0; t < 4; ++t) {
                    int j = t0 + t * 4 + eg;
                    int rcj = __shfl(rcL, j & 63);
                    bool on = (j < ld);
                    nm[t] = on ? __builtin_amdgcn_rcpf((float)(rcj & 63)) : 0.f;
                    unsigned off = ((unsigned)rcj) >> 6;
                    const unsigned short* p = y + (size_t)(on ? off : 0u) + fl * 8;
                    L[t] = *reinterpret_cast<const uint4*>(p);
                }
                #pragma unroll
                for (int t = 0; t < 4; ++t) {
                    fa[0] += nm[t] * bf2f((unsigned short)(L[t].x & 0xFFFF));
                    fa[1] += nm[t] * bf2f((unsigned short)(L[t].x >> 16));
                    fa[2] += nm[t] * bf2f((unsigned short)(L[t].y & 0xFFFF));
                    fa[3] += nm[t] * bf2f((unsigned short)(L[t].y >> 16));
                    fa[4] += nm[t] * bf2f((unsigned short)(L[t].z & 0xFFFF));
                    fa[5] += nm[t] * bf2f((unsigned short)(L[t].z >> 16));
                    fa[6] += nm[t] * bf2f((unsigned short)(L[t].w & 0xFFFF));
                    fa[7] += nm[t] * bf2f((unsigned short)(L[t].w >> 16));
                }
            }
        }
        // reduce across the 4 edge groups
        #pragma unroll
        for (int i = 0; i < 8; ++i) {
            fa[i] += __shfl_xor(fa[i], 16);
            fa[i] += __shfl_xor(fa[i], 32);
        }
    }

    if (eg == 0) {
        if (n < NN) {
            const unsigned short* rp = y + (size_t)n * KC + fl * 8;
            uint4 rv = *reinterpret_cast<const uint4*>(rp);
            float4 b0 = *reinterpret_cast<const float4*>(bias + fl * 8);
            float4 b1 = *reinterpret_cast<const float4*>(bias + fl * 8 + 4);
            float r[8];
            r[0] = bf2f((unsigned short)(rv.x & 0xFFFF)); r[1] = bf2f((unsigned short)(rv.x >> 16));
            r[2] = bf2f((unsigned short)(rv.y & 0xFFFF)); r[3] = bf2f((unsigned short)(rv.y >> 16));
            r[4] = bf2f((unsigned short)(rv.z & 0xFFFF)); r[5] = bf2f((unsigned short)(rv.z >> 16));
            r[6] = bf2f((unsigned short)(rv.w & 0xFFFF)); r[7] = bf2f((unsigned short)(rv.w >> 16));
            float bb[8] = {b0.x, b0.y, b0.z, b0.w, b1.x, b1.y, b1.z, b1.w};
            float v[8];
            #pragma unroll
            for (int i = 0; i < 8; ++i) v[i] = fmaxf(fa[i] + r[i] + bb[i], 0.f);
            if constexpr (!FINAL) {
                uint4 pk;
                unsigned short o[8];
                #pragma unroll
                for (int i = 0; i < 8; ++i) o[i] = f2bf(v[i]);
                pk.x = (unsigned)o[0] | ((unsigned)o[1] << 16);
                pk.y = (unsigned)o[2] | ((unsigned)o[3] << 16);
                pk.z = (unsigned)o[4] | ((unsigned)o[5] << 16);
                pk.w = (unsigned)o[6] | ((unsigned)o[7] << 16);
                *reinterpret_cast<uint4*>(hout + (size_t)n * 128 + fl * 8) = pk;
            } else {
                // note: match reference h3 (bf16 rounded) before fc
                float dp = 0.f;
                #pragma unroll
                for (int i = 0; i < 8; ++i) dp += bf2f(f2bf(v[i])) * fcw[fl * 8 + i];
                dp += __shfl_xor(dp, 1);
                dp += __shfl_xor(dp, 2);
                dp += __shfl_xor(dp, 4);
                dp += __shfl_xor(dp, 8);
                if (fl == 0) fout[n] = dp + fcb[0];
            }
        } else if constexpr (!FINAL) {
            *reinterpret_cast<uint4*>(hout + (size_t)n * 128 + fl * 8) = make_uint4(0, 0, 0, 0);
        }
    }
}

extern "C" void kernel_launch(void* const* d_in, const int* in_sizes, int n_in,
                              void* d_out, int out_size, void* d_ws, size_t ws_size,
                              hipStream_t stream) {
    const float* x     = (const float*)d_in[0];
    const int*   ei    = (const int*)d_in[1];
    const int*   etype = (const int*)d_in[2];
    const float* W[3]    = {(const float*)d_in[3], (const float*)d_in[6], (const float*)d_in[9]};
    const float* root[3] = {(const float*)d_in[4], (const float*)d_in[7], (const float*)d_in[10]};
    const float* bias[3] = {(const float*)d_in[5], (const float*)d_in[8], (const float*)d_in[11]};
    const float* fcw = (const float*)d_in[12];
    const float* fcb = (const float*)d_in[13];
    const int* src = ei;
    const int* dst = ei + EE;

    char* ws = (char*)d_ws;
    auto alloc = [&](size_t bytes) { char* p = ws; ws += (bytes + 255) & ~(size_t)255; return p; };
    int* degRel   = (int*)alloc(NR * sizeof(int));
    int* cursorD  = (int*)alloc(NN * sizeof(int));       // contiguous after degRel
    int* degD     = (int*)alloc(NN * sizeof(int));
    int* segD     = (int*)alloc((NN + 2) * sizeof(int));
    int* bsum     = (int*)alloc(512 * sizeof(int));
    unsigned* rec = (unsigned*)alloc((size_t)EE * sizeof(unsigned));
    unsigned short* Bt2g = (unsigned short*)alloc((size_t)3 * KC * 128 * sizeof(short));
    unsigned short* xbf  = (unsigned short*)alloc((size_t)NPAD * 128 * sizeof(short));
    unsigned short* h1   = (unsigned short*)alloc((size_t)NPAD * 128 * sizeof(short));
    unsigned short* h2   = (unsigned short*)alloc((size_t)NPAD * 128 * sizeof(short));
    unsigned short* yall = (unsigned short*)alloc((size_t)NPAD * KC * sizeof(short));

    // --- graph preprocessing ---
    zero_i32<<<(NR + NN + 255) / 256, 256, 0, stream>>>(degRel, NR + NN);   // degRel + cursorD
    count_deg<<<(EE + 255) / 256, 256, 0, stream>>>(dst, etype, degRel);
    sum8<<<(NN + 255) / 256, 256, 0, stream>>>(degRel, degD);
    const int nScanBlk = (NN + 1023) / 1024;   // 49
    scan1<<<nScanBlk, 256, 0, stream>>>(degD, segD, bsum, NN);
    scan2<<<1, 256, 0, stream>>>(bsum, nScanBlk);
    scan3<<<nScanBlk, 256, 0, stream>>>(segD, bsum, NN);
    set_last<<<1, 1, 0, stream>>>(segD);
    scatter2<<<(EE + 255) / 256, 256, 0, stream>>>(src, dst, etype, segD, degRel, cursorD, rec);

    // --- input conversion + weight panels ---
    xcvt<<<((NPAD * 128 / 4) + 255) / 256, 256, 0, stream>>>(x, xbf);
    const int btN = KC * 128;
    for (int l = 0; l < 3; ++l)
        build_bt2<<<(btN + 255) / 256, 256, 0, stream>>>(W[l], root[l], Bt2g + (size_t)l * btN);

    // --- layers ---
    const int ggrid = NPAD / 64;         // 782
    const int aggGrid = NPAD / 4;        // 12512
    const unsigned short* hin = xbf;
    unsigned short* houts[2] = {h1, h2};
    for (int l = 0; l < 3; ++l) {
        gemm_y<<<ggrid, 256, 0, stream>>>(hin, Bt2g + (size_t)l * btN, yall);
        if (l < 2) {
            agg3<false><<<aggGrid, 256, 0, stream>>>(yall, rec, segD, bias[l], houts[l],
                                                     nullptr, nullptr, nullptr);
            hin = houts[l];
        } else {
            agg3<true><<<aggGrid, 256, 0, stream>>>(yall, rec, segD, bias[l], nullptr,
                                                    fcw, fcb, (float*)d_out);
        }
    }
}